// Round 8
// baseline (465.168 us; speedup 1.0000x reference)
//
#include <hip/hip_runtime.h>
#include <stdint.h>

typedef unsigned long long u64;
typedef unsigned int u32;

#define NA 250000
#define NC 80
#define KP 2000
#define MD 300
#define CAP 4096
#define SCORE_TH 0.05f

// ---- ws layout (bytes) ----
// sbits  u32[250000]      @ 0
// amax   u32[250000]      @ 1000000
// state  u32[16]          @ 2000000   [0]=prefix11 [1]=k [2]=pivot [3]=n_cand [5]=done0 [6]=done1
// hist0  u32[2048]        @ 2000064
// hist1  u32[2048]        @ 2008256
// cand   u64[4096]        @ 2016448
// canda  u32[2048]        @ 2049216
// cands  u32[2048]        @ 2057408
// boxesg float4[2048]     @ 2065600
// sup    u64[2048*32]     @ 2098368

__device__ __forceinline__ u32 ald(const u32* p) {
    return __hip_atomic_load(p, __ATOMIC_RELAXED, __HIP_MEMORY_SCOPE_AGENT);
}
__device__ __forceinline__ void ast(u32* p, u32 v) {
    __hip_atomic_store(p, v, __ATOMIC_RELAXED, __HIP_MEMORY_SCOPE_AGENT);
}

__device__ __forceinline__ u64 readlane_u64(u64 v, int b) {
    u32 lo = (u32)__builtin_amdgcn_readlane((int)(u32)v, b);
    u32 hi = (u32)__builtin_amdgcn_readlane((int)(u32)(v >> 32), b);
    return ((u64)hi << 32) | lo;
}

__device__ __forceinline__ float4 decode_box(const float* __restrict__ anchors,
                                             const float* __restrict__ reg, u32 a) {
    float4 an = ((const float4*)anchors)[a];
    float4 rg = ((const float4*)reg)[a];
    float w = an.z - an.x, h = an.w - an.y;
    float cx = an.x + 0.5f * w, cy = an.y + 0.5f * h;
    float pcx = cx + (rg.x * 0.1f) * w;
    float pcy = cy + (rg.y * 0.1f) * h;
    float pw = expf(rg.z * 0.2f) * w;
    float ph = expf(rg.w * 0.2f) * h;
    float x1 = fmaxf(pcx - 0.5f * pw, 0.0f);
    float y1 = fmaxf(pcy - 0.5f * ph, 0.0f);
    float x2 = fminf(pcx + 0.5f * pw, 512.0f);
    float y2 = fminf(pcy + 0.5f * ph, 512.0f);
    return make_float4(x1, y1, x2, y2);
}

// zero hists + state (poison-safe start of every call)
__global__ void k_init(u32* state, u32* hist0, u32* hist1) {
    int t = threadIdx.x;
    if (t < 16) state[t] = (t == 1) ? (u32)KP : 0u;
    for (int i = t; i < 2048; i += 256) { hist0[i] = 0; hist1[i] = 0; }
}

// pick: find the 2048-bin hist bin containing descending-rank state[1].
__device__ __forceinline__ void pick_body(u32* state, const u32* hist, int p) {
    int lane = threadIdx.x;                   // caller ensures lane<64
    int hi = 2048 - lane * 32;
    int lo = hi - 32;
    u32 h32[32];
#pragma unroll
    for (int x = 0; x < 32; ++x) h32[x] = ald(&hist[lo + x]);
    u32 s = 0;
#pragma unroll
    for (int x = 0; x < 32; ++x) s += h32[x];
    u32 sc = s;
#pragma unroll
    for (int d = 1; d < 64; d <<= 1) {
        u32 tv = __shfl_up(sc, d);
        if (lane >= d) sc += tv;
    }
    u32 pre = sc - s;
    u32 kk = ald(&state[1]);
    if (pre < kk && kk <= sc) {               // exactly one lane
        u32 c = pre; int B = lo;
        for (int x = 31; x >= 0; --x) {
            u32 h = h32[x];
            if (c + h >= kk) { B = lo + x; ast(&state[1], kk - c); break; }
            c += h;
        }
        if (p == 0) ast(&state[0], (u32)B);
        else {
            u32 prefix = ald(&state[0]);
            ast(&state[2], ((prefix << 11) | (u32)B) << 10);   // 22-bit pivot
        }
    }
}

// scores + argmax + fused hist0 (per-block LDS histogram) + fused pick0 (last block).
__global__ __launch_bounds__(256) void k_score(const float* __restrict__ cls,
                                               u32* __restrict__ sbits,
                                               u32* __restrict__ amax,
                                               u32* state, u32* hist0) {
    __shared__ u32 lh[2048];
    __shared__ int is_last;
    int t = threadIdx.x;
    for (int i = t; i < 2048; i += 256) lh[i] = 0;
    int tid = blockIdx.x * 256 + t;
    int a = tid >> 2;
    int k = tid & 3;
    u32 mybits = 0u;
    bool active = (a < NA);
    if (active) {
        const float4* cv = (const float4*)cls;
        int base = a * 20 + k * 5;
        float best = -1e30f; int bi = 0;
#pragma unroll
        for (int j = 0; j < 5; ++j) {
            float4 v = cv[base + j];
            int c0 = k * 20 + j * 4;
            if (v.x > best) { best = v.x; bi = c0; }
            if (v.y > best) { best = v.y; bi = c0 + 1; }
            if (v.z > best) { best = v.z; bi = c0 + 2; }
            if (v.w > best) { best = v.w; bi = c0 + 3; }
        }
#pragma unroll
        for (int m = 1; m <= 2; m <<= 1) {
            float ob = __shfl_xor(best, m);
            int   oi = __shfl_xor(bi, m);
            if (ob > best || (ob == best && oi < bi)) { best = ob; bi = oi; }
        }
        if (k == 0) {
            mybits = (best > SCORE_TH) ? __float_as_uint(best) : 0u;
            sbits[a] = mybits;
            amax[a] = (u32)bi;
        }
    }
    __syncthreads();
    if (active && k == 0) atomicAdd(&lh[mybits >> 21], 1u);
    __syncthreads();
    for (int i = t; i < 2048; i += 256) { u32 h = lh[i]; if (h) atomicAdd(&hist0[i], h); }
    __threadfence();
    if (t == 0) is_last = (atomicAdd(&state[5], 1u) == gridDim.x - 1);
    __syncthreads();
    if (is_last && t < 64) {
        __threadfence();
        pick_body(state, hist0, 0);
    }
}

// hist pass 1 ((bits>>10)&0x7FF, conditional on prefix) with fused pick1.
__global__ __launch_bounds__(256) void k_hist1(const u32* __restrict__ sbits,
                                               u32* hist1, u32* state) {
    __shared__ u32 lh[2048];
    __shared__ int is_last;
    int t = threadIdx.x;
    u32 prefix = state[0];                    // cross-kernel: plain load OK
    for (int i = t; i < 2048; i += 256) lh[i] = 0;
    __syncthreads();
    int idx = blockIdx.x * 1024 + t;
#pragma unroll
    for (int r = 0; r < 4; ++r) {
        int a = idx + r * 256;
        if (a < NA) {
            u32 bb = sbits[a];
            if ((bb >> 21) == prefix) atomicAdd(&lh[(bb >> 10) & 0x7FFu], 1u);
        }
    }
    __syncthreads();
    for (int i = t; i < 2048; i += 256) { u32 h = lh[i]; if (h) atomicAdd(&hist1[i], h); }
    __threadfence();
    if (t == 0) is_last = (atomicAdd(&state[6], 1u) == gridDim.x - 1);
    __syncthreads();
    if (is_last && t < 64) {
        __threadfence();
        pick_body(state, hist1, 1);
    }
}

// collect: per-block LDS aggregation, ONE global atomic per block (256 total).
__global__ __launch_bounds__(256) void k_collect(const u32* __restrict__ sbits,
                                                 u32* state, u64* __restrict__ cand) {
    __shared__ u64 lbuf[1024];
    __shared__ u32 lcount;
    __shared__ u32 gbase;
    int t = threadIdx.x;
    if (t == 0) lcount = 0;
    __syncthreads();
    u32 pivot = state[2];                     // cross-kernel: plain load OK
#pragma unroll
    for (int r = 0; r < 4; ++r) {
        int a = blockIdx.x * 256 + t + r * 65536;
        if (a < NA) {
            u32 b = sbits[a];
            if (b != 0u && b >= pivot) {
                u32 s = atomicAdd(&lcount, 1u);          // LDS atomic, ~13/block
                if (s < 1024u) lbuf[s] = ((u64)b << 32) | (u32)(~(u32)a);
            }
        }
    }
    __syncthreads();
    u32 n = lcount; if (n > 1024u) n = 1024u;
    if (t == 0 && n > 0) gbase = atomicAdd(&state[3], n);
    __syncthreads();
    if (n > 0) {
        u32 base = gbase;
        for (u32 i = t; i < n; i += 256) {
            u32 slot = base + i;
            if (slot < CAP) cand[slot] = lbuf[i];
        }
    }
}

// rank-sort (exact, keys unique) + box decode. 256 blocks x 16 candidates = CAP.
__global__ __launch_bounds__(256) void k_rank(const u32* __restrict__ state,
                                              const u64* __restrict__ cand,
                                              u32* __restrict__ canda, u32* __restrict__ cands,
                                              float4* __restrict__ boxesg,
                                              const float* __restrict__ anchors,
                                              const float* __restrict__ reg) {
    __shared__ u64 tile[CAP];        // 32 KB
    __shared__ u32 pr2[16][17];
    int t = threadIdx.x;
    int n = (int)state[3]; if (n > CAP) n = CAP;
    for (int i = t; i < CAP; i += 256) tile[i] = (i < n) ? cand[i] : 0ull;
    // robustness: zero-fill unsorted tail slots (disjoint from rank writes rk<n)
    if (blockIdx.x == 0) {
        for (int i = n + t; i < 2048; i += 256) {
            canda[i] = 0u; cands[i] = 0u;
            boxesg[i] = make_float4(0.f, 0.f, 0.f, 0.f);
        }
    }
    __syncthreads();
    int li = t & 15, seg = t >> 4;
    u64 my = tile[blockIdx.x * 16 + li];
    u32 r = 0;
    int j0 = seg * 256;
#pragma unroll 8
    for (int j = j0; j < j0 + 256; ++j) r += (tile[j] > my) ? 1u : 0u;
    pr2[li][seg] = r;
    __syncthreads();
    if (t < 16) {
        int ci = blockIdx.x * 16 + t;
        if (ci < n) {
            u32 rk = 0;
#pragma unroll
            for (int s = 0; s < 16; ++s) rk += pr2[t][s];
            u64 kx = tile[ci];
            u32 a = ~((u32)kx);
            if (rk < 2048u) {
                canda[rk] = a;
                cands[rk] = (u32)(kx >> 32);
                boxesg[rk] = decode_box(anchors, reg, a);
            }
        }
    }
}

// IoU suppression bitmask over decoded boxes. 256 blocks x 4 waves = 1024 tiles.
__global__ __launch_bounds__(256) void k_iou(const float4* __restrict__ boxesg,
                                             u64* __restrict__ sup) {
    __shared__ float4 jb[4][64];
    int t = threadIdx.x;
    int w = t >> 6, lane = t & 63;
    int W = blockIdx.x * 4 + w;        // 0..1023
    int bi = W >> 5, bj = W & 31;
    int j0 = bj * 64;
    jb[w][lane] = boxesg[j0 + lane];
    __syncthreads();
    int i = bi * 64 + lane;
    if (i >= KP) return;
    if (bj < bi) { sup[(size_t)i * 32 + bj] = 0ull; return; }
    int jn = KP - j0; if (jn > 64) jn = 64;
    float4 bx = boxesg[i];
    float ai = (bx.z - bx.x) * (bx.w - bx.y);
    u64 word = 0ull;
    for (int jj = 0; jj < jn; ++jj) {
        if (j0 + jj <= i) continue;
        float4 b2 = jb[w][jj];
        float aj = (b2.z - b2.x) * (b2.w - b2.y);
        float xx1 = fmaxf(bx.x, b2.x), yy1 = fmaxf(bx.y, b2.y);
        float xx2 = fminf(bx.z, b2.z), yy2 = fminf(bx.w, b2.w);
        float iw = xx2 - xx1; if (iw < 0.f) iw = 0.f;
        float ih = yy2 - yy1; if (ih < 0.f) ih = 0.f;
        float inter = iw * ih;
        float iou = inter / (ai + aj - inter + 1e-9f);
        if (iou > 0.1f) word |= (1ull << jj);
    }
    sup[(size_t)i * 32 + bj] = word;
}

// serial greedy NMS + fused output, single wave. Loop with unroll-2 (I-cache
// resident body) instead of full unroll; myw/myw1 read from the LDS rows just
// written (dynamic index OK in LDS). Register double-buffer, depth-2 prefetch;
// carry accumulator keeps the kept-row fold one chunk behind the critical path.
__global__ __launch_bounds__(64, 1) void k_scan(const u64* __restrict__ sup,
                                                const u32* __restrict__ cands,
                                                const u32* __restrict__ canda,
                                                const u32* __restrict__ amax,
                                                const float4* __restrict__ boxesg,
                                                float* __restrict__ out) {
    __shared__ u64 rows[2][32 * 65];
    __shared__ int klist[2048];
    int lane = threadIdx.x;

    ulonglong2 bufA[16], bufB[16];
    float cvA, cvB;
    {
        const ulonglong2* s0 = (const ulonglong2*)(sup + (size_t)lane * 32);
#pragma unroll
        for (int q = 0; q < 16; ++q) bufA[q] = s0[q];
        cvA = __uint_as_float(cands[lane]);
        const ulonglong2* s1 = (const ulonglong2*)(sup + (size_t)(64 + lane) * 32);
#pragma unroll
        for (int q = 0; q < 16; ++q) bufB[q] = s1[q];
        cvB = __uint_as_float(cands[64 + lane]);
    }

    u64 removed = 0ull;
    u64 carry = 0ull;
    u64 kmask_prev = 0ull;
    int kc = 0;

#pragma unroll 2
    for (int c = 0; c < 32; ++c) {
        const int p = c & 1;
        ulonglong2* buf = p ? bufB : bufA;
        float cv = p ? cvB : cvA;

#pragma unroll
        for (int q = 0; q < 16; ++q) {
            rows[p][(2 * q) * 65 + lane] = buf[q].x;
            rows[p][(2 * q + 1) * 65 + lane] = buf[q].y;
        }

        u64 curw = carry | readlane_u64(removed, c);
        u64 vm = __ballot(cv > SCORE_TH);
        if (c == 31) vm &= (1ull << (KP - 31 * 64)) - 1ull;

        u64 myw = rows[p][c * 65 + lane];                       // word c of my row
        u64 myw1 = (c < 31) ? rows[p][(c + 1) * 65 + lane] : 0ull;

        u64 rem = vm & ~curw;
        u64 kmask = 0ull, ncarry = 0ull;
        while (rem) {
            int bb = (int)__builtin_ctzll(rem);
            kmask |= (1ull << bb);
            curw |= readlane_u64(myw, bb);
            ncarry |= readlane_u64(myw1, bb);
            rem &= ~curw;
            rem &= ~(1ull << bb);
        }

        if (lane < 32 && kmask_prev) {
            const u64* rb = &rows[p ^ 1][lane * 65];
            u64 tt = kmask_prev;
            while (tt) {
                int b0 = (int)__builtin_ctzll(tt); tt &= tt - 1;
                int b1 = b0, b2 = b0, b3 = b0, b4 = b0, b5 = b0, b6 = b0, b7 = b0;
                if (tt) { b1 = (int)__builtin_ctzll(tt); tt &= tt - 1; }
                if (tt) { b2 = (int)__builtin_ctzll(tt); tt &= tt - 1; }
                if (tt) { b3 = (int)__builtin_ctzll(tt); tt &= tt - 1; }
                if (tt) { b4 = (int)__builtin_ctzll(tt); tt &= tt - 1; }
                if (tt) { b5 = (int)__builtin_ctzll(tt); tt &= tt - 1; }
                if (tt) { b6 = (int)__builtin_ctzll(tt); tt &= tt - 1; }
                if (tt) { b7 = (int)__builtin_ctzll(tt); tt &= tt - 1; }
                removed |= rb[b0] | rb[b1] | rb[b2] | rb[b3] | rb[b4] | rb[b5] | rb[b6] | rb[b7];
            }
        }

        if ((kmask >> lane) & 1ull) {
            int pos = kc + (int)__popcll(kmask & ((1ull << lane) - 1ull));
            klist[pos] = c * 64 + lane;
        }
        kc += (int)__popcll(kmask);
        kmask_prev = kmask;
        carry = ncarry;

        if (c < 30) {
            int r = (c + 2) * 64 + lane;
            int rr = (r >= KP) ? 0 : r;
            const ulonglong2* s2 = (const ulonglong2*)(sup + (size_t)rr * 32);
#pragma unroll
            for (int q = 0; q < 16; ++q) buf[q] = s2[q];
            float ncv = __uint_as_float(cands[r]);
            if (p) cvB = ncv; else cvA = ncv;
        }
    }

    // fused output: 300 slots
    int myci[5];
    u32 mya[5];
#pragma unroll
    for (int r = 0; r < 5; ++r) {
        int s = lane + r * 64;
        myci[r] = (s < MD && s < kc) ? klist[s] : -1;
    }
#pragma unroll
    for (int r = 0; r < 5; ++r) mya[r] = (myci[r] >= 0) ? canda[myci[r]] : 0u;
#pragma unroll
    for (int r = 0; r < 5; ++r) {
        int s = lane + r * 64;
        if (s >= MD) continue;
        if (myci[r] >= 0) {
            int ci = myci[r];
            u32 a = mya[r];
            u32 aa = (a >= NA) ? 0u : a;
            float4 bx = boxesg[ci];
            out[s] = __uint_as_float(cands[ci]);
            out[MD + s] = (float)amax[aa];
            out[2 * MD + 4 * s + 0] = bx.x;
            out[2 * MD + 4 * s + 1] = bx.y;
            out[2 * MD + 4 * s + 2] = bx.z;
            out[2 * MD + 4 * s + 3] = bx.w;
            out[6 * MD + s] = (float)a;
            out[7 * MD + s] = 1.0f;
        } else {
            out[s] = 0.f;
            out[MD + s] = 0.f;
            out[2 * MD + 4 * s + 0] = 0.f;
            out[2 * MD + 4 * s + 1] = 0.f;
            out[2 * MD + 4 * s + 2] = 0.f;
            out[2 * MD + 4 * s + 3] = 0.f;
            out[6 * MD + s] = -1.0f;
            out[7 * MD + s] = 0.f;
        }
    }
}

extern "C" void kernel_launch(void* const* d_in, const int* in_sizes, int n_in,
                              void* d_out, int out_size, void* d_ws, size_t ws_size,
                              hipStream_t stream) {
    const float* anchors = (const float*)d_in[1];
    const float* reg     = (const float*)d_in[2];
    const float* cls     = (const float*)d_in[3];
    float* out = (float*)d_out;
    char* ws = (char*)d_ws;

    u32* sbits    = (u32*)(ws + 0);
    u32* amax     = (u32*)(ws + 1000000);
    u32* state    = (u32*)(ws + 2000000);
    u32* hist0    = (u32*)(ws + 2000064);
    u32* hist1    = (u32*)(ws + 2008256);
    u64* cand     = (u64*)(ws + 2016448);
    u32* canda    = (u32*)(ws + 2049216);
    u32* cands    = (u32*)(ws + 2057408);
    float4* boxesg= (float4*)(ws + 2065600);
    u64* sup      = (u64*)(ws + 2098368);

    hipLaunchKernelGGL(k_init, dim3(1), dim3(256), 0, stream, state, hist0, hist1);
    hipLaunchKernelGGL(k_score, dim3((NA * 4 + 255) / 256), dim3(256), 0, stream,
                       cls, sbits, amax, state, hist0);
    hipLaunchKernelGGL(k_hist1, dim3((NA + 1023) / 1024), dim3(256), 0, stream,
                       sbits, hist1, state);
    hipLaunchKernelGGL(k_collect, dim3(256), dim3(256), 0, stream,
                       sbits, state, cand);
    hipLaunchKernelGGL(k_rank, dim3(256), dim3(256), 0, stream,
                       state, cand, canda, cands, boxesg, anchors, reg);
    hipLaunchKernelGGL(k_iou, dim3(256), dim3(256), 0, stream, boxesg, sup);
    hipLaunchKernelGGL(k_scan, dim3(1), dim3(64), 0, stream,
                       sup, cands, canda, amax, boxesg, out);
}

// Round 9
// 130.547 us; speedup vs baseline: 3.5632x; 3.5632x over previous
//
#include <hip/hip_runtime.h>
#include <stdint.h>

typedef unsigned long long u64;
typedef unsigned int u32;

#define NA 250000
#define NC 80
#define KP 2000
#define MD 300
#define CAP 4096
#define SCORE_TH 0.05f

// ---- ws layout (bytes) ----
// sbits  u32[250000]      @ 0
// amax   u32[250000]      @ 1000000
// state  u32[16]          @ 2000000   [0]=prefix11 [1]=k [2]=pivot [3]=n_cand [5]=done0 [6]=done1
// hist0  u32[2048]        @ 2000064
// hist1  u32[2048]        @ 2008256
// cand   u64[4096]        @ 2016448
// canda  u32[2048]        @ 2049216
// cands  u32[2048]        @ 2057408
// boxesg float4[2048]     @ 2065600
// sup    u64[2048*32]     @ 2098368

__device__ __forceinline__ u32 ald(const u32* p) {
    return __hip_atomic_load(p, __ATOMIC_RELAXED, __HIP_MEMORY_SCOPE_AGENT);
}
__device__ __forceinline__ void ast(u32* p, u32 v) {
    __hip_atomic_store(p, v, __ATOMIC_RELAXED, __HIP_MEMORY_SCOPE_AGENT);
}

__device__ __forceinline__ u64 readlane_u64(u64 v, int b) {
    u32 lo = (u32)__builtin_amdgcn_readlane((int)(u32)v, b);
    u32 hi = (u32)__builtin_amdgcn_readlane((int)(u32)(v >> 32), b);
    return ((u64)hi << 32) | lo;
}

__device__ __forceinline__ float4 decode_box(const float* __restrict__ anchors,
                                             const float* __restrict__ reg, u32 a) {
    float4 an = ((const float4*)anchors)[a];
    float4 rg = ((const float4*)reg)[a];
    float w = an.z - an.x, h = an.w - an.y;
    float cx = an.x + 0.5f * w, cy = an.y + 0.5f * h;
    float pcx = cx + (rg.x * 0.1f) * w;
    float pcy = cy + (rg.y * 0.1f) * h;
    float pw = expf(rg.z * 0.2f) * w;
    float ph = expf(rg.w * 0.2f) * h;
    float x1 = fmaxf(pcx - 0.5f * pw, 0.0f);
    float y1 = fmaxf(pcy - 0.5f * ph, 0.0f);
    float x2 = fminf(pcx + 0.5f * pw, 512.0f);
    float y2 = fminf(pcy + 0.5f * ph, 512.0f);
    return make_float4(x1, y1, x2, y2);
}

// scores + argmax (init fused into block 0): 4 lanes per anchor, 5x float4 each.
// NOTE: no histogram fusion here — per-block hist merges at 3907 blocks created a
// same-address global-RMW storm (R8: 480µs). Histogramming stays in 245-block kernels.
__global__ void k_score(const float* __restrict__ cls, u32* __restrict__ sbits,
                        u32* __restrict__ amax, u32* __restrict__ state,
                        u32* __restrict__ hist0, u32* __restrict__ hist1) {
    int t = threadIdx.x;
    if (blockIdx.x == 0) {
        if (t < 16) state[t] = (t == 1) ? (u32)KP : 0u;
        for (int i = t; i < 2048; i += 256) { hist0[i] = 0; hist1[i] = 0; }
    }
    int tid = blockIdx.x * 256 + t;
    int a = tid >> 2;
    int k = tid & 3;
    if (a >= NA) return;
    const float4* cv = (const float4*)cls;
    int base = a * 20 + k * 5;
    float best = -1e30f; int bi = 0;
#pragma unroll
    for (int j = 0; j < 5; ++j) {
        float4 v = cv[base + j];
        int c0 = k * 20 + j * 4;
        if (v.x > best) { best = v.x; bi = c0; }
        if (v.y > best) { best = v.y; bi = c0 + 1; }
        if (v.z > best) { best = v.z; bi = c0 + 2; }
        if (v.w > best) { best = v.w; bi = c0 + 3; }
    }
#pragma unroll
    for (int m = 1; m <= 2; m <<= 1) {
        float ob = __shfl_xor(best, m);
        int   oi = __shfl_xor(bi, m);
        if (ob > best || (ob == best && oi < bi)) { best = ob; bi = oi; }
    }
    if (k == 0) {
        sbits[a] = (best > SCORE_TH) ? __float_as_uint(best) : 0u;
        amax[a] = (u32)bi;
    }
}

// pick: find the 2048-bin hist bin containing descending-rank state[1].
__device__ __forceinline__ void pick_body(u32* state, const u32* hist, int p) {
    int lane = threadIdx.x;                   // caller ensures lane<64
    int hi = 2048 - lane * 32;
    int lo = hi - 32;
    u32 h32[32];
#pragma unroll
    for (int x = 0; x < 32; ++x) h32[x] = ald(&hist[lo + x]);
    u32 s = 0;
#pragma unroll
    for (int x = 0; x < 32; ++x) s += h32[x];
    u32 sc = s;
#pragma unroll
    for (int d = 1; d < 64; d <<= 1) {
        u32 tv = __shfl_up(sc, d);
        if (lane >= d) sc += tv;
    }
    u32 pre = sc - s;
    u32 kk = ald(&state[1]);
    if (pre < kk && kk <= sc) {               // exactly one lane
        u32 c = pre; int B = lo;
        for (int x = 31; x >= 0; --x) {
            u32 h = h32[x];
            if (c + h >= kk) { B = lo + x; ast(&state[1], kk - c); break; }
            c += h;
        }
        if (p == 0) ast(&state[0], (u32)B);
        else {
            u32 prefix = ald(&state[0]);
            ast(&state[2], ((prefix << 11) | (u32)B) << 10);   // 22-bit pivot
        }
    }
}

// hist pass 0 (bits>>21) with fused pick in the last-arriving block. 245 blocks.
__global__ __launch_bounds__(256) void k_hist0(const u32* __restrict__ sbits,
                                               u32* hist0, u32* state) {
    __shared__ u32 lh[2048];
    __shared__ int is_last;
    int t = threadIdx.x;
    for (int i = t; i < 2048; i += 256) lh[i] = 0;
    __syncthreads();
    int idx = blockIdx.x * 1024 + t;
#pragma unroll
    for (int r = 0; r < 4; ++r) {
        int a = idx + r * 256;
        if (a < NA) atomicAdd(&lh[sbits[a] >> 21], 1u);
    }
    __syncthreads();
    for (int i = t; i < 2048; i += 256) { u32 h = lh[i]; if (h) atomicAdd(&hist0[i], h); }
    __threadfence();
    if (t == 0) is_last = (atomicAdd(&state[5], 1u) == gridDim.x - 1);
    __syncthreads();
    if (is_last && t < 64) {
        __threadfence();
        pick_body(state, hist0, 0);
    }
}

// hist pass 1 ((bits>>10)&0x7FF, conditional on prefix) with fused pick1.
__global__ __launch_bounds__(256) void k_hist1(const u32* __restrict__ sbits,
                                               u32* hist1, u32* state) {
    __shared__ u32 lh[2048];
    __shared__ int is_last;
    int t = threadIdx.x;
    u32 prefix = state[0];                    // cross-kernel: plain load OK
    for (int i = t; i < 2048; i += 256) lh[i] = 0;
    __syncthreads();
    int idx = blockIdx.x * 1024 + t;
#pragma unroll
    for (int r = 0; r < 4; ++r) {
        int a = idx + r * 256;
        if (a < NA) {
            u32 bb = sbits[a];
            if ((bb >> 21) == prefix) atomicAdd(&lh[(bb >> 10) & 0x7FFu], 1u);
        }
    }
    __syncthreads();
    for (int i = t; i < 2048; i += 256) { u32 h = lh[i]; if (h) atomicAdd(&hist1[i], h); }
    __threadfence();
    if (t == 0) is_last = (atomicAdd(&state[6], 1u) == gridDim.x - 1);
    __syncthreads();
    if (is_last && t < 64) {
        __threadfence();
        pick_body(state, hist1, 1);
    }
}

// collect: per-block LDS aggregation, ONE global atomic per block (256 total).
__global__ __launch_bounds__(256) void k_collect(const u32* __restrict__ sbits,
                                                 u32* state, u64* __restrict__ cand) {
    __shared__ u64 lbuf[1024];
    __shared__ u32 lcount;
    __shared__ u32 gbase;
    int t = threadIdx.x;
    if (t == 0) lcount = 0;
    __syncthreads();
    u32 pivot = state[2];                     // cross-kernel: plain load OK
#pragma unroll
    for (int r = 0; r < 4; ++r) {
        int a = blockIdx.x * 256 + t + r * 65536;
        if (a < NA) {
            u32 b = sbits[a];
            if (b != 0u && b >= pivot) {
                u32 s = atomicAdd(&lcount, 1u);          // LDS atomic, ~13/block
                if (s < 1024u) lbuf[s] = ((u64)b << 32) | (u32)(~(u32)a);
            }
        }
    }
    __syncthreads();
    u32 n = lcount; if (n > 1024u) n = 1024u;
    if (t == 0 && n > 0) gbase = atomicAdd(&state[3], n);
    __syncthreads();
    if (n > 0) {
        u32 base = gbase;
        for (u32 i = t; i < n; i += 256) {
            u32 slot = base + i;
            if (slot < CAP) cand[slot] = lbuf[i];
        }
    }
}

// rank-sort (exact, keys unique) + box decode. 256 blocks x 16 candidates = CAP.
__global__ __launch_bounds__(256) void k_rank(const u32* __restrict__ state,
                                              const u64* __restrict__ cand,
                                              u32* __restrict__ canda, u32* __restrict__ cands,
                                              float4* __restrict__ boxesg,
                                              const float* __restrict__ anchors,
                                              const float* __restrict__ reg) {
    __shared__ u64 tile[CAP];        // 32 KB
    __shared__ u32 pr2[16][17];
    int t = threadIdx.x;
    int n = (int)state[3]; if (n > CAP) n = CAP;
    for (int i = t; i < CAP; i += 256) tile[i] = (i < n) ? cand[i] : 0ull;
    // robustness: zero-fill unsorted tail slots (disjoint from rank writes rk<n)
    if (blockIdx.x == 0) {
        for (int i = n + t; i < 2048; i += 256) {
            canda[i] = 0u; cands[i] = 0u;
            boxesg[i] = make_float4(0.f, 0.f, 0.f, 0.f);
        }
    }
    __syncthreads();
    int li = t & 15, seg = t >> 4;
    u64 my = tile[blockIdx.x * 16 + li];
    u32 r = 0;
    int j0 = seg * 256;
#pragma unroll 8
    for (int j = j0; j < j0 + 256; ++j) r += (tile[j] > my) ? 1u : 0u;
    pr2[li][seg] = r;
    __syncthreads();
    if (t < 16) {
        int ci = blockIdx.x * 16 + t;
        if (ci < n) {
            u32 rk = 0;
#pragma unroll
            for (int s = 0; s < 16; ++s) rk += pr2[t][s];
            u64 kx = tile[ci];
            u32 a = ~((u32)kx);
            if (rk < 2048u) {
                canda[rk] = a;
                cands[rk] = (u32)(kx >> 32);
                boxesg[rk] = decode_box(anchors, reg, a);
            }
        }
    }
}

// IoU suppression bitmask over decoded boxes. 256 blocks x 4 waves = 1024 tiles.
__global__ __launch_bounds__(256) void k_iou(const float4* __restrict__ boxesg,
                                             u64* __restrict__ sup) {
    __shared__ float4 jb[4][64];
    int t = threadIdx.x;
    int w = t >> 6, lane = t & 63;
    int W = blockIdx.x * 4 + w;        // 0..1023
    int bi = W >> 5, bj = W & 31;
    int j0 = bj * 64;
    jb[w][lane] = boxesg[j0 + lane];
    __syncthreads();
    int i = bi * 64 + lane;
    if (i >= KP) return;
    if (bj < bi) { sup[(size_t)i * 32 + bj] = 0ull; return; }
    int jn = KP - j0; if (jn > 64) jn = 64;
    float4 bx = boxesg[i];
    float ai = (bx.z - bx.x) * (bx.w - bx.y);
    u64 word = 0ull;
    for (int jj = 0; jj < jn; ++jj) {
        if (j0 + jj <= i) continue;
        float4 b2 = jb[w][jj];
        float aj = (b2.z - b2.x) * (b2.w - b2.y);
        float xx1 = fmaxf(bx.x, b2.x), yy1 = fmaxf(bx.y, b2.y);
        float xx2 = fminf(bx.z, b2.z), yy2 = fminf(bx.w, b2.w);
        float iw = xx2 - xx1; if (iw < 0.f) iw = 0.f;
        float ih = yy2 - yy1; if (ih < 0.f) ih = 0.f;
        float inter = iw * ih;
        float iou = inter / (ai + aj - inter + 1e-9f);
        if (iou > 0.1f) word |= (1ull << jj);
    }
    sup[(size_t)i * 32 + bj] = word;
}

// serial greedy NMS + fused output, single wave. unroll-2 loop (I-cache-resident
// body); myw/myw1 from the LDS rows just written; register double-buffer with
// depth-2 prefetch; carry accumulator keeps the kept-row fold off the critical path.
__global__ __launch_bounds__(64, 1) void k_scan(const u64* __restrict__ sup,
                                                const u32* __restrict__ cands,
                                                const u32* __restrict__ canda,
                                                const u32* __restrict__ amax,
                                                const float4* __restrict__ boxesg,
                                                float* __restrict__ out) {
    __shared__ u64 rows[2][32 * 65];
    __shared__ int klist[2048];
    int lane = threadIdx.x;

    ulonglong2 bufA[16], bufB[16];
    float cvA, cvB;
    {
        const ulonglong2* s0 = (const ulonglong2*)(sup + (size_t)lane * 32);
#pragma unroll
        for (int q = 0; q < 16; ++q) bufA[q] = s0[q];
        cvA = __uint_as_float(cands[lane]);
        const ulonglong2* s1 = (const ulonglong2*)(sup + (size_t)(64 + lane) * 32);
#pragma unroll
        for (int q = 0; q < 16; ++q) bufB[q] = s1[q];
        cvB = __uint_as_float(cands[64 + lane]);
    }

    u64 removed = 0ull;
    u64 carry = 0ull;
    u64 kmask_prev = 0ull;
    int kc = 0;

#pragma unroll 2
    for (int c = 0; c < 32; ++c) {
        const int p = c & 1;
        ulonglong2* buf = p ? bufB : bufA;
        float cv = p ? cvB : cvA;

#pragma unroll
        for (int q = 0; q < 16; ++q) {
            rows[p][(2 * q) * 65 + lane] = buf[q].x;
            rows[p][(2 * q + 1) * 65 + lane] = buf[q].y;
        }

        u64 curw = carry | readlane_u64(removed, c);
        u64 vm = __ballot(cv > SCORE_TH);
        if (c == 31) vm &= (1ull << (KP - 31 * 64)) - 1ull;

        u64 myw = rows[p][c * 65 + lane];                       // word c of my row
        u64 myw1 = (c < 31) ? rows[p][(c + 1) * 65 + lane] : 0ull;

        u64 rem = vm & ~curw;
        u64 kmask = 0ull, ncarry = 0ull;
        while (rem) {
            int bb = (int)__builtin_ctzll(rem);
            kmask |= (1ull << bb);
            curw |= readlane_u64(myw, bb);
            ncarry |= readlane_u64(myw1, bb);
            rem &= ~curw;
            rem &= ~(1ull << bb);
        }

        if (lane < 32 && kmask_prev) {
            const u64* rb = &rows[p ^ 1][lane * 65];
            u64 tt = kmask_prev;
            while (tt) {
                int b0 = (int)__builtin_ctzll(tt); tt &= tt - 1;
                int b1 = b0, b2 = b0, b3 = b0, b4 = b0, b5 = b0, b6 = b0, b7 = b0;
                if (tt) { b1 = (int)__builtin_ctzll(tt); tt &= tt - 1; }
                if (tt) { b2 = (int)__builtin_ctzll(tt); tt &= tt - 1; }
                if (tt) { b3 = (int)__builtin_ctzll(tt); tt &= tt - 1; }
                if (tt) { b4 = (int)__builtin_ctzll(tt); tt &= tt - 1; }
                if (tt) { b5 = (int)__builtin_ctzll(tt); tt &= tt - 1; }
                if (tt) { b6 = (int)__builtin_ctzll(tt); tt &= tt - 1; }
                if (tt) { b7 = (int)__builtin_ctzll(tt); tt &= tt - 1; }
                removed |= rb[b0] | rb[b1] | rb[b2] | rb[b3] | rb[b4] | rb[b5] | rb[b6] | rb[b7];
            }
        }

        if ((kmask >> lane) & 1ull) {
            int pos = kc + (int)__popcll(kmask & ((1ull << lane) - 1ull));
            klist[pos] = c * 64 + lane;
        }
        kc += (int)__popcll(kmask);
        kmask_prev = kmask;
        carry = ncarry;

        if (c < 30) {
            int r = (c + 2) * 64 + lane;
            int rr = (r >= KP) ? 0 : r;
            const ulonglong2* s2 = (const ulonglong2*)(sup + (size_t)rr * 32);
#pragma unroll
            for (int q = 0; q < 16; ++q) buf[q] = s2[q];
            float ncv = __uint_as_float(cands[r]);
            if (p) cvB = ncv; else cvA = ncv;
        }
    }

    // fused output: 300 slots
    int myci[5];
    u32 mya[5];
#pragma unroll
    for (int r = 0; r < 5; ++r) {
        int s = lane + r * 64;
        myci[r] = (s < MD && s < kc) ? klist[s] : -1;
    }
#pragma unroll
    for (int r = 0; r < 5; ++r) mya[r] = (myci[r] >= 0) ? canda[myci[r]] : 0u;
#pragma unroll
    for (int r = 0; r < 5; ++r) {
        int s = lane + r * 64;
        if (s >= MD) continue;
        if (myci[r] >= 0) {
            int ci = myci[r];
            u32 a = mya[r];
            u32 aa = (a >= NA) ? 0u : a;
            float4 bx = boxesg[ci];
            out[s] = __uint_as_float(cands[ci]);
            out[MD + s] = (float)amax[aa];
            out[2 * MD + 4 * s + 0] = bx.x;
            out[2 * MD + 4 * s + 1] = bx.y;
            out[2 * MD + 4 * s + 2] = bx.z;
            out[2 * MD + 4 * s + 3] = bx.w;
            out[6 * MD + s] = (float)a;
            out[7 * MD + s] = 1.0f;
        } else {
            out[s] = 0.f;
            out[MD + s] = 0.f;
            out[2 * MD + 4 * s + 0] = 0.f;
            out[2 * MD + 4 * s + 1] = 0.f;
            out[2 * MD + 4 * s + 2] = 0.f;
            out[2 * MD + 4 * s + 3] = 0.f;
            out[6 * MD + s] = -1.0f;
            out[7 * MD + s] = 0.f;
        }
    }
}

extern "C" void kernel_launch(void* const* d_in, const int* in_sizes, int n_in,
                              void* d_out, int out_size, void* d_ws, size_t ws_size,
                              hipStream_t stream) {
    const float* anchors = (const float*)d_in[1];
    const float* reg     = (const float*)d_in[2];
    const float* cls     = (const float*)d_in[3];
    float* out = (float*)d_out;
    char* ws = (char*)d_ws;

    u32* sbits    = (u32*)(ws + 0);
    u32* amax     = (u32*)(ws + 1000000);
    u32* state    = (u32*)(ws + 2000000);
    u32* hist0    = (u32*)(ws + 2000064);
    u32* hist1    = (u32*)(ws + 2008256);
    u64* cand     = (u64*)(ws + 2016448);
    u32* canda    = (u32*)(ws + 2049216);
    u32* cands    = (u32*)(ws + 2057408);
    float4* boxesg= (float4*)(ws + 2065600);
    u64* sup      = (u64*)(ws + 2098368);

    hipLaunchKernelGGL(k_score, dim3((NA * 4 + 255) / 256), dim3(256), 0, stream,
                       cls, sbits, amax, state, hist0, hist1);
    hipLaunchKernelGGL(k_hist0, dim3((NA + 1023) / 1024), dim3(256), 0, stream,
                       sbits, hist0, state);
    hipLaunchKernelGGL(k_hist1, dim3((NA + 1023) / 1024), dim3(256), 0, stream,
                       sbits, hist1, state);
    hipLaunchKernelGGL(k_collect, dim3(256), dim3(256), 0, stream,
                       sbits, state, cand);
    hipLaunchKernelGGL(k_rank, dim3(256), dim3(256), 0, stream,
                       state, cand, canda, cands, boxesg, anchors, reg);
    hipLaunchKernelGGL(k_iou, dim3(256), dim3(256), 0, stream, boxesg, sup);
    hipLaunchKernelGGL(k_scan, dim3(1), dim3(64), 0, stream,
                       sup, cands, canda, amax, boxesg, out);
}

// Round 10
// 129.893 us; speedup vs baseline: 3.5812x; 1.0050x over previous
//
#include <hip/hip_runtime.h>
#include <stdint.h>

typedef unsigned long long u64;
typedef unsigned int u32;

#define NA 250000
#define NC 80
#define KP 2000
#define MD 300
#define CAP 4096
#define SCORE_TH 0.05f

// ---- ws layout (bytes) ----
// sbits  u32[250000]      @ 0
// amax   u32[250000]      @ 1000000
// state  u32[16]          @ 2000000   [0]=prefix11 [1]=k [2]=pivot [3]=n_cand [5]=done0 [6]=done1
// hist0  u32[2048]        @ 2000064
// hist1  u32[2048]        @ 2008256
// cand   u64[4096]        @ 2016448
// canda  u32[2048]        @ 2049216
// cands  u32[2048]        @ 2057408
// boxesg float4[2048]     @ 2065600
// supT   u64[32][2048]    @ 2098368   (TRANSPOSED suppression bits: supT[w][i] = word w of row i, j>i only)

__device__ __forceinline__ u32 ald(const u32* p) {
    return __hip_atomic_load(p, __ATOMIC_RELAXED, __HIP_MEMORY_SCOPE_AGENT);
}
__device__ __forceinline__ void ast(u32* p, u32 v) {
    __hip_atomic_store(p, v, __ATOMIC_RELAXED, __HIP_MEMORY_SCOPE_AGENT);
}

__device__ __forceinline__ u64 readlane_u64(u64 v, int b) {
    u32 lo = (u32)__builtin_amdgcn_readlane((int)(u32)v, b);
    u32 hi = (u32)__builtin_amdgcn_readlane((int)(u32)(v >> 32), b);
    return ((u64)hi << 32) | lo;
}

__device__ __forceinline__ float4 decode_box(const float* __restrict__ anchors,
                                             const float* __restrict__ reg, u32 a) {
    float4 an = ((const float4*)anchors)[a];
    float4 rg = ((const float4*)reg)[a];
    float w = an.z - an.x, h = an.w - an.y;
    float cx = an.x + 0.5f * w, cy = an.y + 0.5f * h;
    float pcx = cx + (rg.x * 0.1f) * w;
    float pcy = cy + (rg.y * 0.1f) * h;
    float pw = expf(rg.z * 0.2f) * w;
    float ph = expf(rg.w * 0.2f) * h;
    float x1 = fmaxf(pcx - 0.5f * pw, 0.0f);
    float y1 = fmaxf(pcy - 0.5f * ph, 0.0f);
    float x2 = fminf(pcx + 0.5f * pw, 512.0f);
    float y2 = fminf(pcy + 0.5f * ph, 512.0f);
    return make_float4(x1, y1, x2, y2);
}

// scores + argmax (init fused into block 0): 4 lanes per anchor, 5x float4 each.
// NOTE: no histogram fusion here — per-block hist merges at 3907 blocks created a
// same-address global-RMW storm (R8: 480µs). Histogramming stays in 245-block kernels.
__global__ void k_score(const float* __restrict__ cls, u32* __restrict__ sbits,
                        u32* __restrict__ amax, u32* __restrict__ state,
                        u32* __restrict__ hist0, u32* __restrict__ hist1) {
    int t = threadIdx.x;
    if (blockIdx.x == 0) {
        if (t < 16) state[t] = (t == 1) ? (u32)KP : 0u;
        for (int i = t; i < 2048; i += 256) { hist0[i] = 0; hist1[i] = 0; }
    }
    int tid = blockIdx.x * 256 + t;
    int a = tid >> 2;
    int k = tid & 3;
    if (a >= NA) return;
    const float4* cv = (const float4*)cls;
    int base = a * 20 + k * 5;
    float best = -1e30f; int bi = 0;
#pragma unroll
    for (int j = 0; j < 5; ++j) {
        float4 v = cv[base + j];
        int c0 = k * 20 + j * 4;
        if (v.x > best) { best = v.x; bi = c0; }
        if (v.y > best) { best = v.y; bi = c0 + 1; }
        if (v.z > best) { best = v.z; bi = c0 + 2; }
        if (v.w > best) { best = v.w; bi = c0 + 3; }
    }
#pragma unroll
    for (int m = 1; m <= 2; m <<= 1) {
        float ob = __shfl_xor(best, m);
        int   oi = __shfl_xor(bi, m);
        if (ob > best || (ob == best && oi < bi)) { best = ob; bi = oi; }
    }
    if (k == 0) {
        sbits[a] = (best > SCORE_TH) ? __float_as_uint(best) : 0u;
        amax[a] = (u32)bi;
    }
}

// pick: find the 2048-bin hist bin containing descending-rank state[1].
__device__ __forceinline__ void pick_body(u32* state, const u32* hist, int p) {
    int lane = threadIdx.x;                   // caller ensures lane<64
    int hi = 2048 - lane * 32;
    int lo = hi - 32;
    u32 h32[32];
#pragma unroll
    for (int x = 0; x < 32; ++x) h32[x] = ald(&hist[lo + x]);
    u32 s = 0;
#pragma unroll
    for (int x = 0; x < 32; ++x) s += h32[x];
    u32 sc = s;
#pragma unroll
    for (int d = 1; d < 64; d <<= 1) {
        u32 tv = __shfl_up(sc, d);
        if (lane >= d) sc += tv;
    }
    u32 pre = sc - s;
    u32 kk = ald(&state[1]);
    if (pre < kk && kk <= sc) {               // exactly one lane
        u32 c = pre; int B = lo;
        for (int x = 31; x >= 0; --x) {
            u32 h = h32[x];
            if (c + h >= kk) { B = lo + x; ast(&state[1], kk - c); break; }
            c += h;
        }
        if (p == 0) ast(&state[0], (u32)B);
        else {
            u32 prefix = ald(&state[0]);
            ast(&state[2], ((prefix << 11) | (u32)B) << 10);   // 22-bit pivot
        }
    }
}

// hist pass 0 (bits>>21) with fused pick in the last-arriving block. 245 blocks.
__global__ __launch_bounds__(256) void k_hist0(const u32* __restrict__ sbits,
                                               u32* hist0, u32* state) {
    __shared__ u32 lh[2048];
    __shared__ int is_last;
    int t = threadIdx.x;
    for (int i = t; i < 2048; i += 256) lh[i] = 0;
    __syncthreads();
    int idx = blockIdx.x * 1024 + t;
#pragma unroll
    for (int r = 0; r < 4; ++r) {
        int a = idx + r * 256;
        if (a < NA) atomicAdd(&lh[sbits[a] >> 21], 1u);
    }
    __syncthreads();
    for (int i = t; i < 2048; i += 256) { u32 h = lh[i]; if (h) atomicAdd(&hist0[i], h); }
    __threadfence();
    if (t == 0) is_last = (atomicAdd(&state[5], 1u) == gridDim.x - 1);
    __syncthreads();
    if (is_last && t < 64) {
        __threadfence();
        pick_body(state, hist0, 0);
    }
}

// hist pass 1 ((bits>>10)&0x7FF, conditional on prefix) with fused pick1.
__global__ __launch_bounds__(256) void k_hist1(const u32* __restrict__ sbits,
                                               u32* hist1, u32* state) {
    __shared__ u32 lh[2048];
    __shared__ int is_last;
    int t = threadIdx.x;
    u32 prefix = state[0];                    // cross-kernel: plain load OK
    for (int i = t; i < 2048; i += 256) lh[i] = 0;
    __syncthreads();
    int idx = blockIdx.x * 1024 + t;
#pragma unroll
    for (int r = 0; r < 4; ++r) {
        int a = idx + r * 256;
        if (a < NA) {
            u32 bb = sbits[a];
            if ((bb >> 21) == prefix) atomicAdd(&lh[(bb >> 10) & 0x7FFu], 1u);
        }
    }
    __syncthreads();
    for (int i = t; i < 2048; i += 256) { u32 h = lh[i]; if (h) atomicAdd(&hist1[i], h); }
    __threadfence();
    if (t == 0) is_last = (atomicAdd(&state[6], 1u) == gridDim.x - 1);
    __syncthreads();
    if (is_last && t < 64) {
        __threadfence();
        pick_body(state, hist1, 1);
    }
}

// collect: per-block LDS aggregation, ONE global atomic per block (256 total).
__global__ __launch_bounds__(256) void k_collect(const u32* __restrict__ sbits,
                                                 u32* state, u64* __restrict__ cand) {
    __shared__ u64 lbuf[1024];
    __shared__ u32 lcount;
    __shared__ u32 gbase;
    int t = threadIdx.x;
    if (t == 0) lcount = 0;
    __syncthreads();
    u32 pivot = state[2];                     // cross-kernel: plain load OK
#pragma unroll
    for (int r = 0; r < 4; ++r) {
        int a = blockIdx.x * 256 + t + r * 65536;
        if (a < NA) {
            u32 b = sbits[a];
            if (b != 0u && b >= pivot) {
                u32 s = atomicAdd(&lcount, 1u);          // LDS atomic, ~13/block
                if (s < 1024u) lbuf[s] = ((u64)b << 32) | (u32)(~(u32)a);
            }
        }
    }
    __syncthreads();
    u32 n = lcount; if (n > 1024u) n = 1024u;
    if (t == 0 && n > 0) gbase = atomicAdd(&state[3], n);
    __syncthreads();
    if (n > 0) {
        u32 base = gbase;
        for (u32 i = t; i < n; i += 256) {
            u32 slot = base + i;
            if (slot < CAP) cand[slot] = lbuf[i];
        }
    }
}

// rank-sort (exact, keys unique) + box decode. 256 blocks x 16 candidates = CAP.
__global__ __launch_bounds__(256) void k_rank(const u32* __restrict__ state,
                                              const u64* __restrict__ cand,
                                              u32* __restrict__ canda, u32* __restrict__ cands,
                                              float4* __restrict__ boxesg,
                                              const float* __restrict__ anchors,
                                              const float* __restrict__ reg) {
    __shared__ u64 tile[CAP];        // 32 KB
    __shared__ u32 pr2[16][17];
    int t = threadIdx.x;
    int n = (int)state[3]; if (n > CAP) n = CAP;
    for (int i = t; i < CAP; i += 256) tile[i] = (i < n) ? cand[i] : 0ull;
    // robustness: zero-fill unsorted tail slots (disjoint from rank writes rk<n)
    if (blockIdx.x == 0) {
        for (int i = n + t; i < 2048; i += 256) {
            canda[i] = 0u; cands[i] = 0u;
            boxesg[i] = make_float4(0.f, 0.f, 0.f, 0.f);
        }
    }
    __syncthreads();
    int li = t & 15, seg = t >> 4;
    u64 my = tile[blockIdx.x * 16 + li];
    u32 r = 0;
    int j0 = seg * 256;
#pragma unroll 8
    for (int j = j0; j < j0 + 256; ++j) r += (tile[j] > my) ? 1u : 0u;
    pr2[li][seg] = r;
    __syncthreads();
    if (t < 16) {
        int ci = blockIdx.x * 16 + t;
        if (ci < n) {
            u32 rk = 0;
#pragma unroll
            for (int s = 0; s < 16; ++s) rk += pr2[t][s];
            u64 kx = tile[ci];
            u32 a = ~((u32)kx);
            if (rk < 2048u) {
                canda[rk] = a;
                cands[rk] = (u32)(kx >> 32);
                boxesg[rk] = decode_box(anchors, reg, a);
            }
        }
    }
}

// IoU suppression bitmask, TRANSPOSED output: supT[w][i] = word w of row i.
// Stores are now contiguous across lanes (i = bi*64+lane).
__global__ __launch_bounds__(256) void k_iou(const float4* __restrict__ boxesg,
                                             u64* __restrict__ supT) {
    __shared__ float4 jb[4][64];
    int t = threadIdx.x;
    int w = t >> 6, lane = t & 63;
    int W = blockIdx.x * 4 + w;        // 0..1023
    int bi = W >> 5, bj = W & 31;
    int j0 = bj * 64;
    jb[w][lane] = boxesg[j0 + lane];
    __syncthreads();
    int i = bi * 64 + lane;
    if (i >= KP) return;
    if (bj < bi) { supT[(size_t)bj * 2048 + i] = 0ull; return; }
    int jn = KP - j0; if (jn > 64) jn = 64;
    float4 bx = boxesg[i];
    float ai = (bx.z - bx.x) * (bx.w - bx.y);
    u64 word = 0ull;
    for (int jj = 0; jj < jn; ++jj) {
        if (j0 + jj <= i) continue;
        float4 b2 = jb[w][jj];
        float aj = (b2.z - b2.x) * (b2.w - b2.y);
        float xx1 = fmaxf(bx.x, b2.x), yy1 = fmaxf(bx.y, b2.y);
        float xx2 = fminf(bx.z, b2.z), yy2 = fminf(bx.w, b2.w);
        float iw = xx2 - xx1; if (iw < 0.f) iw = 0.f;
        float ih = yy2 - yy1; if (ih < 0.f) ih = 0.f;
        float inter = iw * ih;
        float iou = inter / (ai + aj - inter + 1e-9f);
        if (iou > 0.1f) word |= (1ull << jj);
    }
    supT[(size_t)bj * 2048 + i] = word;
}

// serial greedy NMS + fused output, single wave, transposed-sup edition.
// Per chunk c: myw/myw1 (words c,c+1 of the chunk's 64 rows) arrive as ONE
// coalesced 8B/lane load each (depth-2 prefetch, registers — no LDS stage).
// Fold of chunk c-1's kept rows = column gather supT[w][kept] by lane w<32,
// 16-batch issued BEFORE the greedy loop, OR'd after (latency hides under it).
// Early exit at kc>=MD is exact (suppression flows strictly forward).
__global__ __launch_bounds__(64, 1) void k_scan(const u64* __restrict__ supT,
                                                const u32* __restrict__ cands,
                                                const u32* __restrict__ canda,
                                                const u32* __restrict__ amax,
                                                const float4* __restrict__ boxesg,
                                                float* __restrict__ out) {
    __shared__ int klist[2048];
    int lane = threadIdx.x;

    u64 mywA, myw1A, mywB, myw1B;
    float cvA, cvB;
    {
        int r0 = lane;                       // rows of chunk 0
        mywA  = supT[r0];                    // word 0
        myw1A = supT[2048 + r0];             // word 1
        cvA = __uint_as_float(cands[r0]);
        int r1 = 64 + lane;                  // rows of chunk 1
        mywB  = supT[1 * 2048 + r1];
        myw1B = supT[2 * 2048 + r1];
        cvB = __uint_as_float(cands[r1]);
    }

    u64 removed = 0ull;     // lane w<32: word w, folds complete through chunk c-2
    u64 carry = 0ull;       // word-c contribution from chunk c-1's kept (inline)
    u64 kmask_prev = 0ull;
    int kc = 0;

    for (int c = 0; c < 32; ++c) {
        const int p = c & 1;
        u64 myw  = p ? mywB  : mywA;
        u64 myw1 = p ? myw1B : myw1A;
        float cv = p ? cvB : cvA;

        // issue fold gathers for chunk c-1's kept (16-batch, static reg indices)
        int pb[16];
        u64 tt = kmask_prev;
#pragma unroll
        for (int q = 0; q < 16; ++q) {
            pb[q] = tt ? (int)__builtin_ctzll(tt) : -1;
            if (tt) tt &= tt - 1;
        }
        const u64* col = supT + (size_t)lane * 2048 + (c - 1) * 64;
        u64 g[16];
        if (lane < 32) {
#pragma unroll
            for (int q = 0; q < 16; ++q) g[q] = (pb[q] >= 0) ? col[pb[q]] : 0ull;
        } else {
#pragma unroll
            for (int q = 0; q < 16; ++q) g[q] = 0ull;
        }

        u64 curw = carry | readlane_u64(removed, c);
        u64 vm = __ballot(cv > SCORE_TH);
        if (c == 31) vm &= (1ull << (KP - 31 * 64)) - 1ull;

        // serial greedy within chunk (uniform SALU chain + readlane)
        u64 rem = vm & ~curw;
        u64 kmask = 0ull, ncarry = 0ull;
        while (rem) {
            int bb = (int)__builtin_ctzll(rem);
            kmask |= (1ull << bb);
            curw |= readlane_u64(myw, bb);
            ncarry |= readlane_u64(myw1, bb);
            rem &= ~curw;
            rem &= ~(1ull << bb);
        }

        // consume gathers: fold chunk c-1's kept columns into removed
        if (lane < 32) {
            u64 acc = g[0];
#pragma unroll
            for (int q = 1; q < 16; ++q) acc |= g[q];
            removed |= acc;
            if (tt) {                          // rare: >16 kept in one chunk
                u64 t2 = tt;
                while (t2) {
                    int b = (int)__builtin_ctzll(t2); t2 &= t2 - 1;
                    removed |= col[b];
                }
            }
        }

        if ((kmask >> lane) & 1ull) {
            int pos = kc + (int)__popcll(kmask & ((1ull << lane) - 1ull));
            klist[pos] = c * 64 + lane;
        }
        kc += (int)__popcll(kmask);
        kmask_prev = kmask;
        carry = ncarry;

        if (kc >= MD) break;                   // exact early exit

        // prefetch chunk c+2 (coalesced single loads)
        if (c < 30) {
            int r = (c + 2) * 64 + lane;
            u64 nmyw  = supT[(size_t)(c + 2) * 2048 + r];
            u64 nmyw1 = (c + 2 < 31) ? supT[(size_t)(c + 3) * 2048 + r] : 0ull;
            float ncv = __uint_as_float(cands[r]);
            if (p) { mywB = nmyw; myw1B = nmyw1; cvB = ncv; }
            else   { mywA = nmyw; myw1A = nmyw1; cvA = ncv; }
        }
    }

    // fused output: 300 slots
    int myci[5];
    u32 mya[5];
#pragma unroll
    for (int r = 0; r < 5; ++r) {
        int s = lane + r * 64;
        myci[r] = (s < MD && s < kc) ? klist[s] : -1;
    }
#pragma unroll
    for (int r = 0; r < 5; ++r) mya[r] = (myci[r] >= 0) ? canda[myci[r]] : 0u;
#pragma unroll
    for (int r = 0; r < 5; ++r) {
        int s = lane + r * 64;
        if (s >= MD) continue;
        if (myci[r] >= 0) {
            int ci = myci[r];
            u32 a = mya[r];
            u32 aa = (a >= NA) ? 0u : a;
            float4 bx = boxesg[ci];
            out[s] = __uint_as_float(cands[ci]);
            out[MD + s] = (float)amax[aa];
            out[2 * MD + 4 * s + 0] = bx.x;
            out[2 * MD + 4 * s + 1] = bx.y;
            out[2 * MD + 4 * s + 2] = bx.z;
            out[2 * MD + 4 * s + 3] = bx.w;
            out[6 * MD + s] = (float)a;
            out[7 * MD + s] = 1.0f;
        } else {
            out[s] = 0.f;
            out[MD + s] = 0.f;
            out[2 * MD + 4 * s + 0] = 0.f;
            out[2 * MD + 4 * s + 1] = 0.f;
            out[2 * MD + 4 * s + 2] = 0.f;
            out[2 * MD + 4 * s + 3] = 0.f;
            out[6 * MD + s] = -1.0f;
            out[7 * MD + s] = 0.f;
        }
    }
}

extern "C" void kernel_launch(void* const* d_in, const int* in_sizes, int n_in,
                              void* d_out, int out_size, void* d_ws, size_t ws_size,
                              hipStream_t stream) {
    const float* anchors = (const float*)d_in[1];
    const float* reg     = (const float*)d_in[2];
    const float* cls     = (const float*)d_in[3];
    float* out = (float*)d_out;
    char* ws = (char*)d_ws;

    u32* sbits    = (u32*)(ws + 0);
    u32* amax     = (u32*)(ws + 1000000);
    u32* state    = (u32*)(ws + 2000000);
    u32* hist0    = (u32*)(ws + 2000064);
    u32* hist1    = (u32*)(ws + 2008256);
    u64* cand     = (u64*)(ws + 2016448);
    u32* canda    = (u32*)(ws + 2049216);
    u32* cands    = (u32*)(ws + 2057408);
    float4* boxesg= (float4*)(ws + 2065600);
    u64* supT     = (u64*)(ws + 2098368);

    hipLaunchKernelGGL(k_score, dim3((NA * 4 + 255) / 256), dim3(256), 0, stream,
                       cls, sbits, amax, state, hist0, hist1);
    hipLaunchKernelGGL(k_hist0, dim3((NA + 1023) / 1024), dim3(256), 0, stream,
                       sbits, hist0, state);
    hipLaunchKernelGGL(k_hist1, dim3((NA + 1023) / 1024), dim3(256), 0, stream,
                       sbits, hist1, state);
    hipLaunchKernelGGL(k_collect, dim3(256), dim3(256), 0, stream,
                       sbits, state, cand);
    hipLaunchKernelGGL(k_rank, dim3(256), dim3(256), 0, stream,
                       state, cand, canda, cands, boxesg, anchors, reg);
    hipLaunchKernelGGL(k_iou, dim3(256), dim3(256), 0, stream, boxesg, supT);
    hipLaunchKernelGGL(k_scan, dim3(1), dim3(64), 0, stream,
                       supT, cands, canda, amax, boxesg, out);
}